// Round 17
// baseline (54.691 us; speedup 1.0000x reference)
//
#include <hip/hip_runtime.h>

#define NJ   24
#define BLK  256
#define REP  4                  // redundancy factor (diagnostic: surfaces kernel in rocprof)
#define JREC 5                  // float4 slots per joint record (4 data + 1 pad)
#define QMF4 (NJ * JREC)        // float4 index of (Qm) ; +1 = pm
#define NCPY (NJ * JREC + 2)    // float4s in the LDS constant table
#define INV4PI 0.07957747154594767f

// ---------------------------------------------------------------------------
// DIAGNOSTIC ROUND: R11 kernel (best, 20.36us) launched with REP x the grid;
// redundant blocks recompute and rewrite identical rows (same bytes -> output
// unchanged, deterministic). Purpose: make poe_main top the rocprof table to
// finally read VALUBusy / Occupancy / LDS conflicts for the winning structure.
// ---------------------------------------------------------------------------
__global__ __launch_bounds__(BLK, 8)
void poe_main(const float* __restrict__ x,
              const float* __restrict__ eta,
              const float* __restrict__ M,
              float* __restrict__ out,
              int nBatch, int nReal)
{
    __shared__ float4 sC[NCPY];
    float* sF = (float*)sC;

    const int t = threadIdx.x;
    if (t < NJ) {
        const float w0 = eta[t*6+0], w1 = eta[t*6+1], w2 = eta[t*6+2];
        const float v0 = eta[t*6+3], v1 = eta[t*6+4], v2 = eta[t*6+5];
        const float k  = w0*w0 + w1*w1 + w2*w2;
        const bool  sm = (k < 1e-12f);
        const float invsqk = sm ? 0.0f : rsqrtf(k);
        const float sqk    = k * invsqk;
        const float invk   = invsqk * invsqk;
        const float invk15 = invk * invsqk;
        const float c10 = w1*v2 - w2*v1;
        const float c11 = w2*v0 - w0*v2;
        const float c12 = w0*v1 - w1*v0;
        const float c20 = w1*c12 - w2*c11;
        const float c21 = w2*c10 - w0*c12;
        const float c22 = w0*c11 - w1*c10;
        float* r = sF + t * JREC * 4;
        r[0]  = w0*invsqk;  r[1]  = w1*invsqk;  r[2]  = w2*invsqk;  r[3]  = sqk;
        r[4]  = v0;         r[5]  = v1;         r[6]  = v2;         r[7]  = sqk * INV4PI;
        r[8]  = c10*invk;   r[9]  = c11*invk;   r[10] = c12*invk;   r[11] = 0.0f;
        r[12] = c20*invk15; r[13] = c21*invk15; r[14] = c22*invk15; r[15] = 0.0f;
    } else if (t == NJ) {
        const float w0 = M[0], w1 = M[1], w2 = M[2];
        const float v0 = M[3], v1 = M[4], v2 = M[5];
        const float t2 = w0*w0 + w1*w1 + w2*w2;
        const bool  sm = (t2 < 1e-12f);
        const float t2s  = sm ? 1.0f : t2;
        const float invt = rsqrtf(t2s);
        const float th   = t2s * invt;
        float s, c;
        __sincosf(th, &s, &c);
        const float invt2 = invt * invt;
        const float B = sm ? 0.5f        : (1.0f - c) * invt2;
        const float C = sm ? (1.0f/6.0f) : (th - s) * invt2 * invt;
        float sh, chh;
        __sincosf(0.5f * th, &sh, &chh);
        const float axs = sm ? 0.5f : sh * invt;   // sin(th/2)/th (limit 1/2)
        float* r = sF + QMF4 * 4;
        r[0] = sm ? 1.0f : chh;
        r[1] = axs * w0;  r[2] = axs * w1;  r[3] = axs * w2;
        const float c10 = w1*v2 - w2*v1, c11 = w2*v0 - w0*v2, c12 = w0*v1 - w1*v0;
        const float c20 = w1*c12 - w2*c11, c21 = w2*c10 - w0*c12, c22 = w0*c11 - w1*c10;
        r[4] = v0 + B*c10 + C*c20;
        r[5] = v1 + B*c11 + C*c21;
        r[6] = v2 + B*c12 + C*c22;
        r[7] = 0.0f;
    }

    // ---- fold redundant block index back to the real range ----
    int vb = blockIdx.x;
    vb = (vb >= nReal*2) ? vb - nReal*2 : vb;
    vb = (vb >= nReal)   ? vb - nReal   : vb;

    const int gid = vb * BLK + t;
    const int row = gid >> 2;
    const int q   = gid & 3;
    const bool active = row < nBatch;

    float2 xa = make_float2(0.f,0.f), xb = xa, xc = xa;
    if (active) {
        const float2* xp = (const float2*)(x + (size_t)row * NJ + q * 6);
        xa = xp[0]; xb = xp[1]; xc = xp[2];
    }

    __syncthreads();

    float Qw=1.f, Qx=0.f, Qy=0.f, Qz=0.f;
    float p0=0.f, p1=0.f, p2=0.f;

    const int cbase = q * 6 * JREC;   // float4 index of this lane's first record

#define JSTEP(JJ, A_) do {                                                    \
    const float4 A4 = sC[cbase + (JJ)*JREC + 0];                              \
    const float4 B4 = sC[cbase + (JJ)*JREC + 1];                              \
    const float4 C4 = sC[cbase + (JJ)*JREC + 2];                              \
    const float4 D4 = sC[cbase + (JJ)*JREC + 3];                              \
    const float a    = (A_);                                                  \
    const float hrev = a * B4.w;                                              \
    const float sh   = __builtin_amdgcn_sinf(hrev);                           \
    const float ch   = __builtin_amdgcn_cosf(hrev);                           \
    const float s    = 2.0f * sh * ch;          /* sin(phi)   */              \
    const float cB   = 2.0f * sh * sh;          /* 1-cos(phi) */              \
    const float phi  = a * A4.w;                                              \
    const float g    = phi - s;                                               \
    const float qj0 = fmaf(a, B4.x, fmaf(cB, C4.x, g * D4.x));                \
    const float qj1 = fmaf(a, B4.y, fmaf(cB, C4.y, g * D4.y));                \
    const float qj2 = fmaf(a, B4.z, fmaf(cB, C4.z, g * D4.z));                \
    const float u10 = Qy*qj2 - Qz*qj1;                                        \
    const float u11 = Qz*qj0 - Qx*qj2;                                        \
    const float u12 = Qx*qj1 - Qy*qj0;                                        \
    const float u20 = Qy*u12 - Qz*u11;                                        \
    const float u21 = Qz*u10 - Qx*u12;                                        \
    const float u22 = Qx*u11 - Qy*u10;                                        \
    const float tw  = 2.0f * Qw;                                              \
    p0 = fmaf(tw, u10, fmaf(2.0f, u20, p0 + qj0));                            \
    p1 = fmaf(tw, u11, fmaf(2.0f, u21, p1 + qj1));                            \
    p2 = fmaf(tw, u12, fmaf(2.0f, u22, p2 + qj2));                            \
    const float ex = sh * A4.x, ey = sh * A4.y, ez = sh * A4.z;               \
    const float nQw = Qw*ch - Qx*ex - Qy*ey - Qz*ez;                          \
    const float nQx = Qw*ex + Qx*ch + Qy*ez - Qz*ey;                          \
    const float nQy = Qw*ey - Qx*ez + Qy*ch + Qz*ex;                          \
    const float nQz = Qw*ez + Qx*ey - Qy*ex + Qz*ch;                          \
    Qw=nQw; Qx=nQx; Qy=nQy; Qz=nQz;                                           \
} while (0)

    JSTEP(0, xa.x); JSTEP(1, xa.y); JSTEP(2, xb.x);
    JSTEP(3, xb.y); JSTEP(4, xc.x); JSTEP(5, xc.y);
#undef JSTEP

#define COMBINE(BIT) do {                                                     \
    const float oQw = __shfl_xor(Qw, BIT), oQx = __shfl_xor(Qx, BIT);         \
    const float oQy = __shfl_xor(Qy, BIT), oQz = __shfl_xor(Qz, BIT);         \
    const float op0 = __shfl_xor(p0, BIT), op1 = __shfl_xor(p1, BIT);         \
    const float op2 = __shfl_xor(p2, BIT);                                    \
    const bool up = (q & (BIT)) != 0;   /* self is the SECOND factor */       \
    const float Aw = up ? oQw : Qw, Ax = up ? oQx : Qx;                       \
    const float Ay = up ? oQy : Qy, Az = up ? oQz : Qz;                       \
    const float Ap0 = up ? op0 : p0, Ap1 = up ? op1 : p1, Ap2 = up ? op2 : p2;\
    const float Bw = up ? Qw : oQw, Bx = up ? Qx : oQx;                       \
    const float By = up ? Qy : oQy, Bz = up ? Qz : oQz;                       \
    const float Bp0 = up ? p0 : op0, Bp1 = up ? p1 : op1, Bp2 = up ? p2 : op2;\
    const float u10 = Ay*Bp2 - Az*Bp1;                                        \
    const float u11 = Az*Bp0 - Ax*Bp2;                                        \
    const float u12 = Ax*Bp1 - Ay*Bp0;                                        \
    const float u20 = Ay*u12 - Az*u11;                                        \
    const float u21 = Az*u10 - Ax*u12;                                        \
    const float u22 = Ax*u11 - Ay*u10;                                        \
    const float tw  = 2.0f * Aw;                                              \
    p0 = fmaf(tw, u10, fmaf(2.0f, u20, Ap0 + Bp0));                           \
    p1 = fmaf(tw, u11, fmaf(2.0f, u21, Ap1 + Bp1));                           \
    p2 = fmaf(tw, u12, fmaf(2.0f, u22, Ap2 + Bp2));                           \
    Qw = Aw*Bw - Ax*Bx - Ay*By - Az*Bz;                                       \
    Qx = Aw*Bx + Ax*Bw + Ay*Bz - Az*By;                                       \
    Qy = Aw*By - Ax*Bz + Ay*Bw + Az*Bx;                                       \
    Qz = Aw*Bz + Ax*By - Ay*Bx + Az*Bw;                                       \
} while (0)

    COMBINE(1);
    COMBINE(2);
#undef COMBINE

    // ---- fold exp(M): T = T * Em  (Em = (Qm, pm), re-read from LDS) ----
    {
        const float4 Qm = sC[QMF4];
        const float4 Pm = sC[QMF4 + 1];
        const float u10 = Qy*Pm.z - Qz*Pm.y;
        const float u11 = Qz*Pm.x - Qx*Pm.z;
        const float u12 = Qx*Pm.y - Qy*Pm.x;
        const float u20 = Qy*u12 - Qz*u11;
        const float u21 = Qz*u10 - Qx*u12;
        const float u22 = Qx*u11 - Qy*u10;
        const float tw  = 2.0f * Qw;
        p0 = fmaf(tw, u10, fmaf(2.0f, u20, p0 + Pm.x));
        p1 = fmaf(tw, u11, fmaf(2.0f, u21, p1 + Pm.y));
        p2 = fmaf(tw, u12, fmaf(2.0f, u22, p2 + Pm.z));
        const float nQw = Qw*Qm.x - Qx*Qm.y - Qy*Qm.z - Qz*Qm.w;
        const float nQx = Qw*Qm.y + Qx*Qm.x + Qy*Qm.w - Qz*Qm.z;
        const float nQy = Qw*Qm.z - Qx*Qm.w + Qy*Qm.x + Qz*Qm.y;
        const float nQz = Qw*Qm.w + Qx*Qm.z - Qy*Qm.y + Qz*Qm.x;
        Qw=nQw; Qx=nQx; Qy=nQy; Qz=nQz;
    }

    // ---- Q -> R, pick my row, store (coalesced 16B/lane) ----
    if (active) {
        const float xx = Qx*Qx, yy = Qy*Qy, zz = Qz*Qz;
        const float xy = Qx*Qy, xz = Qx*Qz, yz = Qy*Qz;
        const float wx = Qw*Qx, wy = Qw*Qy, wz = Qw*Qz;
        const float R00 = 1.0f - 2.0f*(yy + zz);
        const float R01 = 2.0f*(xy - wz);
        const float R02 = 2.0f*(xz + wy);
        const float R10 = 2.0f*(xy + wz);
        const float R11 = 1.0f - 2.0f*(xx + zz);
        const float R12 = 2.0f*(yz - wx);
        const float R20 = 2.0f*(xz - wy);
        const float R21 = 2.0f*(yz + wx);
        const float R22 = 1.0f - 2.0f*(xx + yy);

        float4 mine;
        if      (q == 0) mine = make_float4(R00, R01, R02, p0);
        else if (q == 1) mine = make_float4(R10, R11, R12, p1);
        else if (q == 2) mine = make_float4(R20, R21, R22, p2);
        else             mine = make_float4(0.0f, 0.0f, 0.0f, 1.0f);

        ((float4*)out)[(size_t)row * 4 + q] = mine;
    }
}

extern "C" void kernel_launch(void* const* d_in, const int* in_sizes, int n_in,
                              void* d_out, int out_size, void* d_ws, size_t ws_size,
                              hipStream_t stream)
{
    const float* x   = (const float*)d_in[0];
    const float* eta = (const float*)d_in[1];
    const float* M   = (const float*)d_in[2];
    float* out = (float*)d_out;

    const int nBatch   = in_sizes[0] / NJ;
    const int nThreads = nBatch * 4;
    const int nReal    = (nThreads + BLK - 1) / BLK;
    const int grid     = nReal * REP;   // redundant blocks rewrite identical rows

    poe_main<<<grid, BLK, 0, stream>>>(x, eta, M, out, nBatch, nReal);
}